// Round 7
// baseline (7640.918 us; speedup 1.0000x reference)
//
#include <hip/hip_runtime.h>
#include <stdint.h>
#include <math.h>

#define T 4096
#define NTAGS 6
#define START_TAG 3
#define STOP_TAG 4
#define NEGV -10000.0f

__device__ __forceinline__ float sigm_fast(float z) {
  return 1.f / (1.f + __expf(-z));
}
__device__ __forceinline__ float tanh_fast(float z) {
  return 1.f - 2.f / (1.f + __expf(2.f * z));   // exact at +/-inf saturation
}

typedef _Float16 half2v __attribute__((ext_vector_type(2)));
__device__ __forceinline__ float dot2acc(unsigned a, unsigned b, float c) {
  return __builtin_amdgcn_fdot2(__builtin_bit_cast(half2v, a),
                                __builtin_bit_cast(half2v, b), c, false);
}
__device__ __forceinline__ unsigned short f16b(float x) {
  _Float16 h = (_Float16)x;
  return __builtin_bit_cast(unsigned short, h);
}

// Fast-path handoff (OPPORTUNISTIC, same-XCD only): sc0 store = write-through
// to the producer's L2; sc0 load = bypass L1, read the consumer's L2. If
// producer+consumer share an XCD this is ~L2 latency. If not, the consumer
// just never sees the tag here and falls back to the AGENT-scope slow ring.
__device__ __forceinline__ unsigned long long load_l2(
    const unsigned long long* p) {
  unsigned long long v;
  asm volatile("global_load_dwordx2 %0, %1, off sc0\n\ts_waitcnt vmcnt(0)"
               : "=v"(v) : "v"(p) : "memory");
  return v;
}
__device__ __forceinline__ void store_l2(unsigned long long* p,
                                         unsigned long long v) {
  asm volatile("global_store_dwordx2 %0, %1, off sc0"
               :: "v"(p), "v"(v) : "memory");
}

// ---------------------------------------------------------------------------
// K0: transpose w_ih (both dirs) into wT[k][col], col = d*1024+g; combined bias
// ---------------------------------------------------------------------------
__global__ __launch_bounds__(256) void k0_prep(
    const float* __restrict__ wf, const float* __restrict__ wb,
    const float* __restrict__ bif, const float* __restrict__ bhf,
    const float* __restrict__ bib, const float* __restrict__ bhb,
    float* __restrict__ wT, float* __restrict__ bias2) {
  int idx = blockIdx.x * 256 + threadIdx.x;   // 0 .. 524287
  int k = idx >> 11, col = idx & 2047;
  int d = col >> 10, g = col & 1023;
  const float* w = d ? wb : wf;
  wT[idx] = w[g * 256 + k];                   // wT[k*2048 + col]
  if (idx < 2048) bias2[idx] = d ? (bib[g] + bhb[g]) : (bif[g] + bhf[g]);
}

// ---------------------------------------------------------------------------
// K1: zpre[d][t][g] = emb[sent[t]] . w_ih[d][g] + b_ih + b_hh
// ---------------------------------------------------------------------------
__global__ __launch_bounds__(256) void k1_zpre(
    const int* __restrict__ sent, const float* __restrict__ emb,
    const float* __restrict__ wT, const float* __restrict__ bias2,
    float* __restrict__ zpre) {
  int tb = blockIdx.x, cb = blockIdx.y;
  int tid = threadIdx.x;
  int col = cb * 256 + tid;
  int d = col >> 10, g = col & 1023;
  __shared__ float xs[32 * 256];
  int t0 = tb * 32;
  for (int r = 0; r < 32; r++) {
    int s = sent[t0 + r];                       // uniform -> scalar broadcast
    xs[r * 256 + tid] = emb[(size_t)s * 256 + tid];
  }
  __syncthreads();
  float acc[32];
#pragma unroll
  for (int r = 0; r < 32; r++) acc[r] = 0.f;
  const float4* xs4 = (const float4*)xs;
  for (int kq = 0; kq < 64; kq++) {
    float w0 = wT[(4 * kq + 0) * 2048 + col];
    float w1 = wT[(4 * kq + 1) * 2048 + col];
    float w2 = wT[(4 * kq + 2) * 2048 + col];
    float w3 = wT[(4 * kq + 3) * 2048 + col];
#pragma unroll
    for (int r = 0; r < 32; r++) {
      float4 x4 = xs4[r * 64 + kq];             // uniform address -> broadcast
      acc[r] += w0 * x4.x + w1 * x4.y + w2 * x4.z + w3 * x4.w;
    }
  }
  float bb = bias2[col];
  for (int r = 0; r < 32; r++)
    zpre[((size_t)d * T + (t0 + r)) * 1024 + g] = acc[r] + bb;
}

// ---------------------------------------------------------------------------
// K2 v6: BiLSTM recurrence, 16 participant WGs (blockIdx%8==0 of 128 -> all
// on XCD 0 IF dispatch is round-robin; that mapping is a heuristic only).
// Hybrid handoff: fast ring (sc0 stores + sc0 polls; L2-coherent when
// same-XCD) with guaranteed fallback to a slow ring (AGENT-scope atomics,
// MALL; the round-1..5 proven protocol). Identical data on both paths ->
// no hang possible, wrong placement only costs speed.
// Per WG: 32 cells -> 128 gate rows x 256 k, f16 weights in 64 KB LDS,
// k-split across 4 waves (wave q: k in [64q,64q+64), wave-private h slice,
// lane-contiguous conflict-free b128 reads). 2 barriers/step.
// ---------------------------------------------------------------------------
__global__ __launch_bounds__(256) void k2_lstm(
    const float* __restrict__ zpre,
    const float* __restrict__ whf, const float* __restrict__ whb,
    const float* __restrict__ h0, const float* __restrict__ c0,
    float* h_all, unsigned long long* fastr, unsigned long long* slowr) {
  if (blockIdx.x % 8 != 0) return;           // XCD-0 heuristic (speed only)
  int slot = blockIdx.x / 8;                 // 0..15
  int d = slot >> 3, sub = slot & 7;
  const float* w_hh = d ? whb : whf;
  int tid = threadIdx.x;
  int q = tid >> 6, lane = tid & 63;

  __shared__ uint4 wl4[32 * 128];                   // 64 KB f16 weights
  __shared__ __align__(16) unsigned hq[4][32];      // per-wave h2 slices
  __shared__ float z_part[4][128];                  // per-wave partial z

  // stage weights once: k = 64*sq + 8*sm + sj at ((sq*8+sm)*128 + r)*8 + sj
  {
    unsigned short* wlh = (unsigned short*)wl4;
    for (int idx = tid; idx < 128 * 256; idx += 256) {
      int r = idx >> 8, k = idx & 255;
      int gate = r >> 5, cell = r & 31;
      float wv = w_hh[(size_t)(gate * 256 + sub * 32 + cell) * 256 + k];
      int sq = k >> 6, sm = (k >> 3) & 7, sj = k & 7;
      wlh[((sq * 8 + sm) * 128 + r) * 8 + sj] = f16b(wv);
    }
  }
  // h0 into wave slices (wave q needs h[64q .. 64q+64))
  if (lane < 32) {
    float f0 = h0[d * 256 + q * 64 + 2 * lane];
    float f1 = h0[d * 256 + q * 64 + 2 * lane + 1];
    hq[q][lane] = (unsigned)f16b(f0) | ((unsigned)f16b(f1) << 16);
  }
  float c = 0.f;
  if (tid < 32) c = c0[d * 256 + sub * 32 + tid];

  const float* zp_d = zpre + (size_t)d * T * 1024;
  float* h_d = h_all + (size_t)d * T * 256;
  unsigned long long* f_rg = fastr + (size_t)d * 256;
  unsigned long long* s_rg = slowr + (size_t)d * 256;

  // zpre for s=0 held by the 32 updater threads (4 gates each)
  float zv4[4] = {0.f, 0.f, 0.f, 0.f};
  if (tid < 32) {
    int t0 = d ? (T - 1) : 0;
#pragma unroll
    for (int g = 0; g < 4; g++)
      zv4[g] = zp_d[(size_t)t0 * 1024 + g * 256 + sub * 32 + tid];
  }
  __syncthreads();                                  // staging + h0 visible

  for (int s = 0; s < T; s++) {
    int t = d ? (T - 1 - s) : s;

    // poll FIRST; then issue the next-step zpre prefetch (so the poll's
    // vmcnt(0) never waits on the prefetch)
    if (s > 0 && lane < 32) {
      unsigned exp_tag = (unsigned)s;               // producer tagged s-1 as s
      int ridx = ((s - 1) & 1) * 128 + q * 32 + lane;
      const unsigned long long* fa = &f_rg[ridx];
      unsigned long long v;
      for (;;) {
        bool got = false;
#pragma unroll 1
        for (int it = 0; it < 4; ++it) {
          v = load_l2(fa);                          // fast: L2 if same-XCD
          if ((unsigned)(v >> 32) == exp_tag) { got = true; break; }
        }
        if (got) break;
        v = __hip_atomic_load(&s_rg[ridx], __ATOMIC_RELAXED,
                              __HIP_MEMORY_SCOPE_AGENT);  // guaranteed path
        if ((unsigned)(v >> 32) == exp_tag) break;
      }
      hq[q][lane] = (unsigned)v;
    }
    __builtin_amdgcn_wave_barrier();                // order hq write vs reads

    // prefetch next-step zpre; consumed a full step later
    float zn4[4] = {0.f, 0.f, 0.f, 0.f};
    if (tid < 32 && s + 1 < T) {
      int tn = d ? (t - 1) : (t + 1);
#pragma unroll
      for (int g = 0; g < 4; g++)
        zn4[g] = zp_d[(size_t)tn * 1024 + g * 256 + sub * 32 + tid];
    }

    // dot: wave q, rows rA=lane, rB=64+lane, k in [64q,64q+64)
    const uint4* hq4 = (const uint4*)(&hq[q][0]);
    float accA = 0.f, accB = 0.f;
#pragma unroll
    for (int m = 0; m < 8; m++) {
      uint4 hv4 = hq4[m];                           // wave-uniform broadcast
      uint4 wA = wl4[(q * 8 + m) * 128 + lane];     // lane-contiguous b128
      uint4 wB = wl4[(q * 8 + m) * 128 + 64 + lane];
      accA = dot2acc(wA.x, hv4.x, accA); accA = dot2acc(wA.y, hv4.y, accA);
      accA = dot2acc(wA.z, hv4.z, accA); accA = dot2acc(wA.w, hv4.w, accA);
      accB = dot2acc(wB.x, hv4.x, accB); accB = dot2acc(wB.y, hv4.y, accB);
      accB = dot2acc(wB.z, hv4.z, accB); accB = dot2acc(wB.w, hv4.w, accB);
    }
    z_part[q][lane] = accA;
    z_part[q][64 + lane] = accB;
    __syncthreads();                                // (1) partials ready

    if (tid < 32) {
      float a[4];
#pragma unroll
      for (int g = 0; g < 4; g++) {
        int r = g * 32 + tid;
        float z = z_part[0][r] + z_part[1][r] + z_part[2][r] + z_part[3][r]
                + zv4[g];
        a[g] = (g == 2) ? tanh_fast(z) : sigm_fast(z);
      }
      c = a[1] * c + a[0] * a[2];
      float hvl = a[3] * tanh_fast(c);
      h_d[(size_t)t * 256 + sub * 32 + tid] = hvl;  // fp32 history for k3
      float hn = __shfl_down(hvl, 1);
      if ((tid & 1) == 0) {                         // 2 f16 h per tagged 8B
        unsigned h2 = (unsigned)f16b(hvl) | ((unsigned)f16b(hn) << 16);
        unsigned long long pkt =
            ((unsigned long long)(unsigned)(s + 1) << 32) | h2;
        int widx = (s & 1) * 128 + sub * 16 + (tid >> 1);
        store_l2(&f_rg[widx], pkt);                 // fast ring (L2)
        __hip_atomic_store(&s_rg[widx], pkt, __ATOMIC_RELAXED,
                           __HIP_MEMORY_SCOPE_AGENT);  // slow ring (MALL)
      }
#pragma unroll
      for (int g = 0; g < 4; g++) zv4[g] = zn4[g];
    }
    __syncthreads();                                // (2) z_part reuse safe
  }
}

// ---------------------------------------------------------------------------
// K3: feats[t][tag] = [hf[t]; hb[t]] . W_out[tag] + b_out[tag]
// ---------------------------------------------------------------------------
__global__ __launch_bounds__(64) void k3_feats(
    const float* __restrict__ h_all, const float* __restrict__ Wout,
    const float* __restrict__ bout, float* __restrict__ feats) {
  int t = blockIdx.x;
  int j = threadIdx.x;
  const float* hf = h_all + (size_t)t * 256;
  const float* hb = h_all + (size_t)T * 256 + (size_t)t * 256;
  float s[6];
#pragma unroll
  for (int g = 0; g < 6; g++) s[g] = 0.f;
#pragma unroll
  for (int m = 0; m < 4; m++) {
    float a = hf[j + 64 * m];
#pragma unroll
    for (int g = 0; g < 6; g++) s[g] += a * Wout[g * 512 + j + 64 * m];
  }
#pragma unroll
  for (int m = 0; m < 4; m++) {
    float b = hb[j + 64 * m];
#pragma unroll
    for (int g = 0; g < 6; g++) s[g] += b * Wout[g * 512 + 256 + j + 64 * m];
  }
#pragma unroll
  for (int g = 0; g < 6; g++) {
#pragma unroll
    for (int off = 32; off >= 1; off >>= 1) s[g] += __shfl_xor(s[g], off);
  }
  if (j < 6) feats[(size_t)t * 6 + j] = s[j] + bout[j];
}

// ---------------------------------------------------------------------------
// K4: Viterbi forward (serial, first-max argmax like jnp.argmax) + parallel
// backtrace via 6-entry map-composition suffix scan. Single wave.
// ---------------------------------------------------------------------------
__global__ __launch_bounds__(64) void k4_viterbi(
    const float* __restrict__ feats, const float* __restrict__ trans,
    float* __restrict__ out) {
  __shared__ unsigned char bp_lds[T * 8];
  __shared__ float fbuf[2][64 * 6];
  int lane = threadIdx.x;

  float tr[6];
#pragma unroll
  for (int f = 0; f < 6; f++) tr[f] = (lane < 6) ? trans[lane * 6 + f] : 0.f;
  float fv = (lane == START_TAG) ? 0.f : NEGV;

  for (int idx = lane; idx < 384; idx += 64) fbuf[0][idx] = feats[idx];

  for (int cch = 0; cch < 64; cch++) {
    float pf[6];
    if (cch + 1 < 64) {
#pragma unroll
      for (int m = 0; m < 6; m++)
        pf[m] = feats[(cch + 1) * 384 + lane + 64 * m];   // prefetch in regs
    }
    const float* fb = fbuf[cch & 1];
    for (int j = 0; j < 64; j++) {
      int t = cch * 64 + j;
      float best = -3.4e38f;
      int bi = 0;
#pragma unroll
      for (int f = 0; f < 6; f++) {
        float v = __shfl(fv, f) + tr[f];     // trans[to][from] + fv[from]
        if (v > best) { best = v; bi = f; }  // strict > => first max index
      }
      float nfv = best + fb[j * 6 + (lane < 6 ? lane : 0)];
      if (lane < 6) {
        fv = nfv;
        bp_lds[t * 8 + lane] = (unsigned char)bi;
      }
    }
    if (cch + 1 < 64) {
#pragma unroll
      for (int m = 0; m < 6; m++)
        fbuf[(cch + 1) & 1][lane + 64 * m] = pf[m];
    }
  }

  float term = (lane < 6) ? (fv + trans[STOP_TAG * 6 + lane]) : -3.4e38f;
  float bestv = -3.4e38f;
  int bestt = 0;
#pragma unroll
  for (int f = 0; f < 6; f++) {
    float v = __shfl(term, f);
    if (v > bestv) { bestv = v; bestt = f; }
  }
  if (lane == 0) out[0] = bestv;

  // backtrace: path[t] = S_t(best), S_t = M_{t+1} o ... o M_{T-1}
  unsigned int ident = 0;
#pragma unroll
  for (int i = 0; i < 6; i++) ident |= (unsigned)i << (3 * i);

  unsigned int p = ident;                 // P_L = M_{64L} o ... o M_{64L+63}
  int base = lane * 64;
  for (int j2 = 0; j2 < 64; j2++) {
    const unsigned int* bw = (const unsigned int*)&bp_lds[(base + j2) * 8];
    unsigned int lo = bw[0], hi = bw[1];
    unsigned int mw = (lo & 7) | (((lo >> 8) & 7) << 3) | (((lo >> 16) & 7) << 6)
                    | (((lo >> 24) & 7) << 9) | ((hi & 7) << 12)
                    | (((hi >> 8) & 7) << 15);
    unsigned int np = 0;
#pragma unroll
    for (int i = 0; i < 6; i++) {
      unsigned int b = (mw >> (3 * i)) & 7;
      np |= ((p >> (3 * b)) & 7) << (3 * i);   // p := p o M_t
    }
    p = np;
  }
  unsigned int suf = p;   // suffix scan: suf_L = P_L o ... o P_63
#pragma unroll
  for (int off = 1; off < 64; off <<= 1) {
    unsigned int other = __shfl_down(suf, off);
    if (lane + off < 64) {
      unsigned int ns = 0;
#pragma unroll
      for (int i = 0; i < 6; i++) {
        unsigned int b = (other >> (3 * i)) & 7;
        ns |= ((suf >> (3 * b)) & 7) << (3 * i);   // suf := suf o other
      }
      suf = ns;
    }
  }
  unsigned int tail = __shfl_down(suf, 1);     // Suf_{L+1}
  if (lane == 63) tail = ident;
  unsigned int cur = tail;                     // = S_{64L+63}
  for (int j2 = 63; j2 >= 0; j2--) {
    int t = base + j2;
    out[1 + t] = (float)((cur >> (3 * bestt)) & 7);
    const unsigned int* bw = (const unsigned int*)&bp_lds[t * 8];
    unsigned int lo = bw[0], hi = bw[1];
    unsigned int mw = (lo & 7) | (((lo >> 8) & 7) << 3) | (((lo >> 16) & 7) << 6)
                    | (((lo >> 24) & 7) << 9) | ((hi & 7) << 12)
                    | (((hi >> 8) & 7) << 15);
    unsigned int nc = 0;
#pragma unroll
    for (int i = 0; i < 6; i++) {
      unsigned int b = (cur >> (3 * i)) & 7;
      nc |= ((mw >> (3 * b)) & 7) << (3 * i);  // cur := M_t o cur
    }
    cur = nc;
  }
}

// ---------------------------------------------------------------------------
extern "C" void kernel_launch(void* const* d_in, const int* in_sizes, int n_in,
                              void* d_out, int out_size, void* d_ws, size_t ws_size,
                              hipStream_t stream) {
  const int*   sent  = (const int*)d_in[0];
  const float* emb   = (const float*)d_in[1];
  const float* wihf  = (const float*)d_in[2];
  const float* whhf  = (const float*)d_in[3];
  const float* bihf  = (const float*)d_in[4];
  const float* bhhf  = (const float*)d_in[5];
  const float* wihb  = (const float*)d_in[6];
  const float* whhb  = (const float*)d_in[7];
  const float* bihb  = (const float*)d_in[8];
  const float* bhhb  = (const float*)d_in[9];
  const float* Wout  = (const float*)d_in[10];
  const float* bout  = (const float*)d_in[11];
  const float* trans = (const float*)d_in[12];
  const float* h0    = (const float*)d_in[13];
  const float* c0    = (const float*)d_in[14];
  float* out = (float*)d_out;

  char* ws = (char*)d_ws;
  float*              zpre  = (float*)(ws + 0);          // 32 MiB
  float*              h_all = (float*)(ws + 33554432);   //  8 MiB
  float*              wT    = (float*)(ws + 41943040);   //  2 MiB
  float*              bias2 = (float*)(ws + 44040192);   //  8 KiB
  float*              feats = (float*)(ws + 44048384);   // 96 KiB
  unsigned long long* fastr = (unsigned long long*)(ws + 44146688); // 4 KiB
  unsigned long long* slowr = (unsigned long long*)(ws + 44150784); // 4 KiB

  k0_prep<<<2048, 256, 0, stream>>>(wihf, wihb, bihf, bhhf, bihb, bhhb, wT, bias2);
  dim3 g1(128, 8);
  k1_zpre<<<g1, 256, 0, stream>>>(sent, emb, wT, bias2, zpre);
  k2_lstm<<<128, 256, 0, stream>>>(zpre, whhf, whhb, h0, c0, h_all, fastr, slowr);
  k3_feats<<<4096, 64, 0, stream>>>(h_all, Wout, bout, feats);
  k4_viterbi<<<1, 64, 0, stream>>>(feats, trans, out);
}